// Round 12
// baseline (229.137 us; speedup 1.0000x reference)
//
#include <hip/hip_runtime.h>

#define T_  4
#define B_  2
#define C_  384
#define L_  1024
#define H_  8
#define C2_ 768
#define S_  (B_*C_*L_)

typedef __attribute__((ext_vector_type(8))) short short8;
typedef __attribute__((ext_vector_type(4))) float floatx4;
typedef __attribute__((ext_vector_type(16))) float floatx16;

__device__ __forceinline__ unsigned bf16_rne(float v) {
    unsigned u = __float_as_uint(v);
    u += 0x7FFFu + ((u >> 16) & 1u);
    return u >> 16;
}
__device__ __forceinline__ float bf16_to_f(unsigned h) { return __uint_as_float(h << 16); }
__device__ __forceinline__ void split3(float v, unsigned& hi, unsigned& mi, unsigned& lo) {
    hi = bf16_rne(v);
    float r1 = v - bf16_to_f(hi);
    mi = bf16_rne(r1);
    float r2 = r1 - bf16_to_f(mi);
    lo = bf16_rne(r2);
}

// ============ K0: split BOTH fp32 weight tensors into 3 bf16 planes ========
__global__ __launch_bounds__(256) void split_w2(
    const float* __restrict__ Wa, int n4a,
    unsigned short* __restrict__ hia, unsigned short* __restrict__ mia,
    unsigned short* __restrict__ loa,
    const float* __restrict__ Wb, int n4b,
    unsigned short* __restrict__ hib, unsigned short* __restrict__ mib,
    unsigned short* __restrict__ lob) {
    int i = blockIdx.x * 256 + threadIdx.x;
    const float* W; unsigned short *hi, *mi, *lo;
    if (i < n4a) { W = Wa; hi = hia; mi = mia; lo = loa; }
    else {
        i -= n4a;
        if (i >= n4b) return;
        W = Wb; hi = hib; mi = mib; lo = lob;
    }
    float4 v = ((const float4*)W)[i];
    float vv[4] = {v.x, v.y, v.z, v.w};
    union { unsigned short us[4]; uint2 u2; } h, m, l;
#pragma unroll
    for (int e = 0; e < 4; e++) {
        unsigned hh, mm, ll; split3(vv[e], hh, mm, ll);
        h.us[e] = (unsigned short)hh; m.us[e] = (unsigned short)mm; l.us[e] = (unsigned short)ll;
    }
    ((uint2*)hi)[i] = h.u2; ((uint2*)mi)[i] = m.u2; ((uint2*)lo)[i] = l.u2;
}

// ============ K1/K5: mem_update scan over T + bf16 spike transpose =========
__global__ __launch_bounds__(256) void scan_transpose(const float* __restrict__ src,
                                                      unsigned short* __restrict__ dstT) {
    __shared__ unsigned short tile[64][72];
    const int tid = threadIdx.x;
    const int l0 = blockIdx.x * 64, c0 = blockIdx.y * 64, b = blockIdx.z;
    const int row = tid >> 2, seg = tid & 3;
    float mem[16], sp[16];
#pragma unroll
    for (int e = 0; e < 16; e++) { mem[e] = 0.f; sp[e] = 0.f; }
    for (int t = 0; t < T_; t++) {
        const size_t base = ((size_t)((t*B_ + b)*C_ + c0 + row))*L_ + l0 + seg*16;
#pragma unroll
        for (int qq = 0; qq < 4; qq++) {
            float4 v = *(const float4*)(src + base + qq*4);
            float vv[4] = {v.x, v.y, v.z, v.w};
            unsigned bs[4];
#pragma unroll
            for (int s = 0; s < 4; s++) {
                int e = qq*4 + s;
                mem[e] = mem[e]*0.25f*(1.f - sp[e]) + vv[s];
                bool sb = mem[e] > 0.5f;
                sp[e] = sb ? 1.f : 0.f;
                bs[s] = sb ? 0x3F80u : 0u;
            }
            *(unsigned*)&tile[row][seg*16 + qq*4]     = bs[0] | (bs[1] << 16);
            *(unsigned*)&tile[row][seg*16 + qq*4 + 2] = bs[2] | (bs[3] << 16);
        }
        __syncthreads();
        {
            const int lr = tid >> 2, cs = tid & 3;
#pragma unroll
            for (int sub = 0; sub < 2; sub++) {
                unsigned wv[4];
#pragma unroll
                for (int p = 0; p < 4; p++) {
                    unsigned e0 = tile[cs*16 + sub*8 + p*2][lr];
                    unsigned e1 = tile[cs*16 + sub*8 + p*2 + 1][lr];
                    wv[p] = e0 | (e1 << 16);
                }
                uint4 o; o.x = wv[0]; o.y = wv[1]; o.z = wv[2]; o.w = wv[3];
                *(uint4*)(dstT + ((size_t)(t*B_ + b)*L_ + l0 + lr)*C_ + c0 + cs*16 + sub*8) = o;
            }
        }
        __syncthreads();
    }
}

// ============ K2: y = BN1(W @ xs) via MFMA, 96m x 64l tile, aliased LDS ====
__global__ __launch_bounds__(256) void gemm1_mfma(
    const unsigned short* __restrict__ whi, const unsigned short* __restrict__ wmi,
    const unsigned short* __restrict__ wlo, const unsigned short* __restrict__ xsT,
    const float* __restrict__ g, const float* __restrict__ be,
    const float* __restrict__ mn, const float* __restrict__ vr,
    unsigned short* __restrict__ y1hi, unsigned short* __restrict__ y1mi,
    unsigned short* __restrict__ y1lo,
    unsigned short* __restrict__ y2hi, unsigned short* __restrict__ y2mi,
    unsigned short* __restrict__ y2lo) {
    __shared__ unsigned short smem[14080];
    const int tid = threadIdx.x;
    const int flat = blockIdx.x;
    const int tb = flat & 7;
    const int ii = flat >> 3;
    const int mt = ii >> 4, lt = ii & 15;
    const int l0 = lt * 64;
    const int w = tid >> 6, lane = tid & 63;
    const int q = lane >> 4, n15 = lane & 15;
    const int mw = (w & 1) * 48, lw = (w >> 1) * 32;

    floatx4 acc[3][2];
#pragma unroll
    for (int i = 0; i < 3; i++)
#pragma unroll
        for (int j = 0; j < 2; j++) acc[i][j] = (floatx4){0.f,0.f,0.f,0.f};

    for (int ck = 0; ck < C_; ck += 32) {
#pragma unroll
        for (int p = 0; p < 3; p++) {
            const unsigned short* wp = p == 0 ? whi : p == 1 ? wmi : wlo;
            unsigned short* ap = smem + p*3840;
            for (int s = tid; s < 384; s += 256) {
                int r = s >> 2, c = s & 3;
                *(uint4*)&ap[r*40 + c*8] = *(const uint4*)(wp + (size_t)(mt*96 + r)*C_ + ck + c*8);
            }
        }
        {
            int r = tid >> 2, c = tid & 3;
            *(uint4*)&smem[11520 + r*40 + c*8] =
                *(const uint4*)(xsT + ((size_t)tb*L_ + l0 + r)*C_ + ck + c*8);
        }
        __syncthreads();
        short8 bb[2];
#pragma unroll
        for (int in = 0; in < 2; in++)
            bb[in] = *(short8*)&smem[11520 + (lw + in*16 + n15)*40 + q*8];
#pragma unroll
        for (int im = 0; im < 3; im++) {
            short8 ah = *(short8*)&smem[       (mw + im*16 + n15)*40 + q*8];
            short8 am = *(short8*)&smem[3840 + (mw + im*16 + n15)*40 + q*8];
            short8 al = *(short8*)&smem[7680 + (mw + im*16 + n15)*40 + q*8];
#pragma unroll
            for (int in = 0; in < 2; in++) {
                acc[im][in] = __builtin_amdgcn_mfma_f32_16x16x32_bf16(ah, bb[in], acc[im][in], 0,0,0);
                acc[im][in] = __builtin_amdgcn_mfma_f32_16x16x32_bf16(am, bb[in], acc[im][in], 0,0,0);
                acc[im][in] = __builtin_amdgcn_mfma_f32_16x16x32_bf16(al, bb[in], acc[im][in], 0,0,0);
            }
        }
        __syncthreads();
    }

#pragma unroll
    for (int im = 0; im < 3; im++)
#pragma unroll
        for (int r = 0; r < 4; r++) {
            int o = mt*96 + mw + im*16 + q*4 + r;
            float inv = g[o] / sqrtf(vr[o] + 1e-5f);
            float sh = be[o] - mn[o]*inv;
#pragma unroll
            for (int in = 0; in < 2; in++)
                acc[im][in][r] = acc[im][in][r]*inv + sh;
        }
    const bool isY1 = ((w & 1) == 0);
#pragma unroll
    for (int p = 0; p < 3; p++) {
        if (isY1) {
#pragma unroll
            for (int im = 0; im < 3; im++)
#pragma unroll
                for (int in = 0; in < 2; in++) {
                    union { unsigned short us[4]; uint2 u2; } pk;
#pragma unroll
                    for (int r = 0; r < 4; r++) {
                        unsigned hh = bf16_rne(acc[im][in][r]);
                        pk.us[r] = (unsigned short)hh;
                        acc[im][in][r] -= bf16_to_f(hh);
                    }
                    *(uint2*)&smem[(lw + in*16 + n15)*56 + im*16 + q*4] = pk.u2;
                }
        } else {
#pragma unroll
            for (int im = 0; im < 3; im++)
#pragma unroll
                for (int in = 0; in < 2; in++)
#pragma unroll
                    for (int r = 0; r < 4; r++) {
                        unsigned hh = bf16_rne(acc[im][in][r]);
                        smem[3584 + (im*16 + q*4 + r)*72 + lw + in*16 + n15] = (unsigned short)hh;
                        acc[im][in][r] -= bf16_to_f(hh);
                    }
        }
        __syncthreads();
        unsigned short* y1p = p == 0 ? y1hi : p == 1 ? y1mi : y1lo;
        unsigned short* y2p = p == 0 ? y2hi : p == 1 ? y2mi : y2lo;
        for (int s = tid; s < 384; s += 256) {
            int r1 = s / 6, c8 = s % 6;
            *(uint4*)(y1p + (((size_t)tb*H_ + mt)*L_ + l0 + r1)*48 + c8*8) =
                *(uint4*)&smem[r1*56 + c8*8];
        }
        for (int s = tid; s < 384; s += 256) {
            int cr = s >> 3, lq = s & 7;
            *(uint4*)(y2p + ((size_t)tb*C_ + mt*48 + cr)*L_ + l0 + lq*8) =
                *(uint4*)&smem[3584 + cr*72 + lq*8];
        }
        __syncthreads();
    }
}

// ============ K3: attn = y1^T @ xr (32x32x16 MFMA, K=48 exact) =============
// Tile 64l x 128m; grid 2048 flat, XCD-swizzled (2 bh slices per XCD).
// Each wave: 32l sub (i) x two 32m subs (j0, j0+2).
__global__ __launch_bounds__(256) void attn_spike_mfma(
    const unsigned short* __restrict__ y1hi, const unsigned short* __restrict__ y1mi,
    const unsigned short* __restrict__ y1lo, const unsigned short* __restrict__ xsT,
    unsigned* __restrict__ bits) {
    __shared__ unsigned short A_hi[64][56], A_mi[64][56], A_lo[64][56];
    __shared__ unsigned short B_s[128][56];
    __shared__ unsigned bits_s[128][2];
    const int tid = threadIdx.x;
    const int flat = blockIdx.x;
    const int xcd = flat & 7;
    const int ii = flat >> 3;                 // 0..255
    const int bh = xcd*2 + (ii >> 7);         // XCD-pinned (b,h)
    const int rr = ii & 127;
    const int b = bh >> 3, h = bh & 7;
    const int lbase = (rr >> 3)*64, mbase = (rr & 7)*128;
    const int w = tid >> 6, lane = tid & 63;
    const int l31 = lane & 31, half = lane >> 5;
    const int i = w & 1, j0 = w >> 1;         // l-subtile; first m-subtile

    float mem[2][16];
#pragma unroll
    for (int jj = 0; jj < 2; jj++)
#pragma unroll
        for (int r = 0; r < 16; r++) mem[jj][r] = 0.f;

    for (int t = 0; t < T_; t++) {
        const int tb = t*B_ + b;
        const size_t yb = (((size_t)tb*H_ + h)*L_ + lbase)*48;
        const size_t xb = ((size_t)tb*L_ + mbase)*C_ + h*48;
        for (int s = tid; s < 384; s += 256) {          // y1: 64 rows x 6 chunks
            int r = s / 6, c = s % 6;
            size_t ro = yb + (size_t)r*48 + c*8;
            *(uint4*)&A_hi[r][c*8] = *(const uint4*)(y1hi + ro);
            *(uint4*)&A_mi[r][c*8] = *(const uint4*)(y1mi + ro);
            *(uint4*)&A_lo[r][c*8] = *(const uint4*)(y1lo + ro);
        }
        for (int s = tid; s < 768; s += 256) {          // xsT: 128 rows x 6 chunks
            int r = s / 6, c = s % 6;
            *(uint4*)&B_s[r][c*8] = *(const uint4*)(xsT + xb + (size_t)r*C_ + c*8);
        }
        bits_s[tid >> 1][tid & 1] = 0u;
        __syncthreads();

        short8 ah[3], am[3], al[3];
#pragma unroll
        for (int ks = 0; ks < 3; ks++) {
            const int kcol = ks*16 + half*8;
            ah[ks] = *(short8*)&A_hi[i*32 + l31][kcol];
            am[ks] = *(short8*)&A_mi[i*32 + l31][kcol];
            al[ks] = *(short8*)&A_lo[i*32 + l31][kcol];
        }
#pragma unroll
        for (int jj = 0; jj < 2; jj++) {
            const int j = j0 + jj*2;
            floatx16 acc = {0.f,0.f,0.f,0.f,0.f,0.f,0.f,0.f,0.f,0.f,0.f,0.f,0.f,0.f,0.f,0.f};
#pragma unroll
            for (int ks = 0; ks < 3; ks++) {
                short8 bb = *(short8*)&B_s[j*32 + l31][ks*16 + half*8];
                acc = __builtin_amdgcn_mfma_f32_32x32x16_bf16(ah[ks], bb, acc, 0,0,0);
                acc = __builtin_amdgcn_mfma_f32_32x32x16_bf16(am[ks], bb, acc, 0,0,0);
                acc = __builtin_amdgcn_mfma_f32_32x32x16_bf16(al[ks], bb, acc, 0,0,0);
            }
            unsigned word = 0;
#pragma unroll
            for (int r = 0; r < 16; r++) {
                float m = (mem[jj][r] > 0.5f ? 0.f : mem[jj][r]*0.25f) + acc[r];
                mem[jj][r] = m;
                int lloc = (r & 3) + 8*(r >> 2) + 4*half;
                word |= (m > 0.5f) ? (1u << lloc) : 0u;
            }
            atomicOr(&bits_s[j*32 + l31][i], word);
        }
        __syncthreads();
        {
            int m = tid >> 1, wd = tid & 1;
            bits[((size_t)(tb*H_ + h)*L_ + mbase + m)*32 + (lbase >> 5) + wd] = bits_s[m][wd];
        }
        __syncthreads();
    }
}

// ============ K4: outpre = y2 @ spikes (16x16x32, B unpacked from bits) ====
__global__ __launch_bounds__(256) void attn_out_mfma(
    const unsigned short* __restrict__ y2hi, const unsigned short* __restrict__ y2mi,
    const unsigned short* __restrict__ y2lo,
    const unsigned* __restrict__ bits, float* __restrict__ outpre) {
    __shared__ unsigned short A_hi[48][72], A_mi[48][72], A_lo[48][72];
    const int tid = threadIdx.x;
    const int flat = blockIdx.x;
    const int xcd = flat & 7;
    const int ii = flat >> 3;
    const int tbh = xcd*8 + (ii >> 4);
    const int mtile = ii & 15;
    const int t = tbh >> 4, b = (tbh >> 3) & 1, h = tbh & 7;
    const int tb = t*B_ + b;
    const int w = tid >> 6, lane = tid & 63;
    const int q = lane >> 4, n15 = lane & 15;
    const int mb = mtile*64 + w*16;

    floatx4 acc[3];
#pragma unroll
    for (int i = 0; i < 3; i++) acc[i] = (floatx4){0.f,0.f,0.f,0.f};

    const unsigned* brow = bits + ((size_t)(tb*H_ + h)*L_ + mb + n15)*32;
    const size_t y2b = ((size_t)tb*C_ + h*48)*L_;

    for (int lt = 0; lt < L_; lt += 64) {
        for (int s = tid; s < 384; s += 256) {
            int r = s >> 3, c = s & 7;
            size_t ro = y2b + (size_t)r*L_ + lt + c*8;
            *(uint4*)&A_hi[r][c*8] = *(const uint4*)(y2hi + ro);
            *(uint4*)&A_mi[r][c*8] = *(const uint4*)(y2mi + ro);
            *(uint4*)&A_lo[r][c*8] = *(const uint4*)(y2lo + ro);
        }
        uint2 bw = *(const uint2*)(brow + (lt >> 5));
        __syncthreads();
#pragma unroll
        for (int kc = 0; kc < 2; kc++) {
            unsigned word = kc ? bw.y : bw.x;
            unsigned byt = (word >> (q*8)) & 0xFFu;
            union { unsigned u[4]; short8 v; } bu;
#pragma unroll
            for (int p = 0; p < 4; p++)
                bu.u[p] = (((byt >> (2*p)) & 1u) ? 0x3F80u : 0u)
                        | (((byt >> (2*p+1)) & 1u) ? 0x3F800000u : 0u);
            short8 bfrag = bu.v;
#pragma unroll
            for (int i = 0; i < 3; i++) {
                int ra = i*16 + n15;
                short8 ah = *(short8*)&A_hi[ra][kc*32 + q*8];
                short8 am = *(short8*)&A_mi[ra][kc*32 + q*8];
                short8 al = *(short8*)&A_lo[ra][kc*32 + q*8];
                acc[i] = __builtin_amdgcn_mfma_f32_16x16x32_bf16(ah, bfrag, acc[i], 0,0,0);
                acc[i] = __builtin_amdgcn_mfma_f32_16x16x32_bf16(am, bfrag, acc[i], 0,0,0);
                acc[i] = __builtin_amdgcn_mfma_f32_16x16x32_bf16(al, bfrag, acc[i], 0,0,0);
            }
        }
        __syncthreads();
    }
#pragma unroll
    for (int i = 0; i < 3; i++)
#pragma unroll
        for (int r = 0; r < 4; r++) {
            int d = i*16 + q*4 + r;
            outpre[((size_t)tb*C_ + h*48 + d)*L_ + mb + n15] = acc[i][r];
        }
}

// ============ K6: out = BN2(proj @ outs) + x (MFMA, 96x64 tile) ============
__global__ __launch_bounds__(256) void gemm2_mfma(
    const unsigned short* __restrict__ whi, const unsigned short* __restrict__ wmi,
    const unsigned short* __restrict__ wlo, const unsigned short* __restrict__ xT,
    const float* __restrict__ g, const float* __restrict__ be,
    const float* __restrict__ mn, const float* __restrict__ vr,
    const float* __restrict__ res, float* __restrict__ out) {
    __shared__ unsigned short A_hi[96][40], A_mi[96][40], A_lo[96][40];
    __shared__ unsigned short B_s[64][40];
    const int tid = threadIdx.x;
    const int tb = blockIdx.y;
    const int mt = blockIdx.x >> 4, lt = blockIdx.x & 15;
    const int l0 = lt * 64;
    const int w = tid >> 6, lane = tid & 63;
    const int q = lane >> 4, n15 = lane & 15;
    const int mw = (w & 1) * 48, lw = (w >> 1) * 32;

    floatx4 acc[3][2];
#pragma unroll
    for (int i = 0; i < 3; i++)
#pragma unroll
        for (int j = 0; j < 2; j++) acc[i][j] = (floatx4){0.f,0.f,0.f,0.f};

    for (int ck = 0; ck < C_; ck += 32) {
#pragma unroll
        for (int p = 0; p < 3; p++) {
            const unsigned short* wp = p == 0 ? whi : p == 1 ? wmi : wlo;
            unsigned short (*ap)[40] = p == 0 ? A_hi : p == 1 ? A_mi : A_lo;
            for (int s = tid; s < 384; s += 256) {
                int r = s >> 2, c = s & 3;
                *(uint4*)&ap[r][c*8] = *(const uint4*)(wp + (size_t)(mt*96 + r)*C_ + ck + c*8);
            }
        }
        {
            int r = tid >> 2, c4 = tid & 3;
            *(uint4*)&B_s[r][c4*8] = *(const uint4*)(xT + ((size_t)tb*L_ + l0 + r)*C_ + ck + c4*8);
        }
        __syncthreads();
        short8 bb[2];
#pragma unroll
        for (int in = 0; in < 2; in++)
            bb[in] = *(short8*)&B_s[lw + in*16 + n15][q*8];
#pragma unroll
        for (int im = 0; im < 3; im++) {
            short8 ah = *(short8*)&A_hi[mw + im*16 + n15][q*8];
            short8 am = *(short8*)&A_mi[mw + im*16 + n15][q*8];
            short8 al = *(short8*)&A_lo[mw + im*16 + n15][q*8];
#pragma unroll
            for (int in = 0; in < 2; in++) {
                acc[im][in] = __builtin_amdgcn_mfma_f32_16x16x32_bf16(ah, bb[in], acc[im][in], 0,0,0);
                acc[im][in] = __builtin_amdgcn_mfma_f32_16x16x32_bf16(am, bb[in], acc[im][in], 0,0,0);
                acc[im][in] = __builtin_amdgcn_mfma_f32_16x16x32_bf16(al, bb[in], acc[im][in], 0,0,0);
            }
        }
        __syncthreads();
    }
#pragma unroll
    for (int im = 0; im < 3; im++)
#pragma unroll
        for (int r = 0; r < 4; r++) {
            int o = mt*96 + mw + im*16 + q*4 + r;
            float inv = g[o] / sqrtf(vr[o] + 1e-5f);
            float sh = be[o] - mn[o]*inv;
#pragma unroll
            for (int in = 0; in < 2; in++) {
                int l = l0 + lw + in*16 + n15;
                size_t idx = ((size_t)tb*C_ + o)*L_ + l;
                out[idx] = acc[im][in][r]*inv + sh + res[idx];
            }
        }
}

extern "C" void kernel_launch(void* const* d_in, const int* in_sizes, int n_in,
                              void* d_out, int out_size, void* d_ws, size_t ws_size,
                              hipStream_t stream) {
    const float* x   = (const float*)d_in[0];
    const float* W_w = (const float*)d_in[1];
    const float* g1  = (const float*)d_in[2];
    const float* b1  = (const float*)d_in[3];
    const float* m1  = (const float*)d_in[4];
    const float* v1  = (const float*)d_in[5];
    const float* pw  = (const float*)d_in[6];
    const float* g2  = (const float*)d_in[7];
    const float* b2  = (const float*)d_in[8];
    const float* m2  = (const float*)d_in[9];
    const float* v2  = (const float*)d_in[10];

    float* ws = (float*)d_ws;
    unsigned short* xsT  = (unsigned short*)ws;               // 1,572,864 f
    unsigned short* y1hi = (unsigned short*)(ws + 1572864);   // 1,572,864 f each
    unsigned short* y1mi = (unsigned short*)(ws + 3145728);
    unsigned short* y1lo = (unsigned short*)(ws + 4718592);
    unsigned short* y2hi = (unsigned short*)(ws + 6291456);
    unsigned short* y2mi = (unsigned short*)(ws + 7864320);
    unsigned short* y2lo = (unsigned short*)(ws + 9437184);
    unsigned*       bits = (unsigned*)(ws + 11010048);        // ends 13,107,200 f
    unsigned short* wspl[3]  = {(unsigned short*)(ws + 13107200),
                                (unsigned short*)(ws + 13254656),
                                (unsigned short*)(ws + 13402112)};
    unsigned short* pwspl[3] = {(unsigned short*)(ws + 13549568),
                                (unsigned short*)(ws + 13623296),
                                (unsigned short*)(ws + 13697024)};  // ends 13,770,752 f = 55.1 MB
    float*          outpre = (float*)(ws + 1572864);          // alias y1hi+y1mi (dead after K3)
    unsigned short* outsT  = (unsigned short*)(ws + 4718592); // alias y1lo (dead after K3)
    float* out = (float*)d_out;

    // 0) split both weight tensors into bf16 planes (one launch)
    split_w2<<<dim3(432), 256, 0, stream>>>(W_w, C2_*C_/4, wspl[0], wspl[1], wspl[2],
                                            pw,  C_*C_/4, pwspl[0], pwspl[1], pwspl[2]);
    // 1) xs spikes (exact fp32 scan) -> bf16, transposed [tb][l][c]
    scan_transpose<<<dim3(16, 6, B_), 256, 0, stream>>>(x, xsT);
    // 2) y = BN1(W @ xs): 96x64 tile, aliased LDS, 1024 blocks XCD-swizzled
    gemm1_mfma<<<dim3(1024), 256, 0, stream>>>(wspl[0], wspl[1], wspl[2], xsT,
                                               g1, b1, m1, v1,
                                               y1hi, y1mi, y1lo, y2hi, y2mi, y2lo);
    // 3) attn spikes: 64l x 128m tile, grid 2048 XCD-swizzled
    attn_spike_mfma<<<dim3(2048), 256, 0, stream>>>(y1hi, y1mi, y1lo, xsT, bits);
    // 4) outpre = y2 @ spikes: MFMA, XCD-swizzled 1D grid
    attn_out_mfma<<<dim3(1024), 256, 0, stream>>>(y2hi, y2mi, y2lo, bits, outpre);
    // 5) outs spikes -> bf16 transposed
    scan_transpose<<<dim3(16, 6, B_), 256, 0, stream>>>(outpre, outsT);
    // 6) out = BN2(proj @ outs) + x
    gemm2_mfma<<<dim3(64, 8), 256, 0, stream>>>(pwspl[0], pwspl[1], pwspl[2], outsT,
                                                g2, b2, m2, v2, x, out);
}

// Round 13
// 220.973 us; speedup vs baseline: 1.0369x; 1.0369x over previous
//
#include <hip/hip_runtime.h>

#define T_  4
#define B_  2
#define C_  384
#define L_  1024
#define H_  8
#define C2_ 768
#define S_  (B_*C_*L_)

typedef __attribute__((ext_vector_type(8))) short short8;
typedef __attribute__((ext_vector_type(4))) float floatx4;
typedef __attribute__((ext_vector_type(16))) float floatx16;

__device__ __forceinline__ unsigned bf16_rne(float v) {
    unsigned u = __float_as_uint(v);
    u += 0x7FFFu + ((u >> 16) & 1u);
    return u >> 16;
}
__device__ __forceinline__ float bf16_to_f(unsigned h) { return __uint_as_float(h << 16); }
__device__ __forceinline__ void split3(float v, unsigned& hi, unsigned& mi, unsigned& lo) {
    hi = bf16_rne(v);
    float r1 = v - bf16_to_f(hi);
    mi = bf16_rne(r1);
    float r2 = r1 - bf16_to_f(mi);
    lo = bf16_rne(r2);
}

// ============ K0: split BOTH fp32 weight tensors into 3 bf16 planes ========
__global__ __launch_bounds__(256) void split_w2(
    const float* __restrict__ Wa, int n4a,
    unsigned short* __restrict__ hia, unsigned short* __restrict__ mia,
    unsigned short* __restrict__ loa,
    const float* __restrict__ Wb, int n4b,
    unsigned short* __restrict__ hib, unsigned short* __restrict__ mib,
    unsigned short* __restrict__ lob) {
    int i = blockIdx.x * 256 + threadIdx.x;
    const float* W; unsigned short *hi, *mi, *lo;
    if (i < n4a) { W = Wa; hi = hia; mi = mia; lo = loa; }
    else {
        i -= n4a;
        if (i >= n4b) return;
        W = Wb; hi = hib; mi = mib; lo = lob;
    }
    float4 v = ((const float4*)W)[i];
    float vv[4] = {v.x, v.y, v.z, v.w};
    union { unsigned short us[4]; uint2 u2; } h, m, l;
#pragma unroll
    for (int e = 0; e < 4; e++) {
        unsigned hh, mm, ll; split3(vv[e], hh, mm, ll);
        h.us[e] = (unsigned short)hh; m.us[e] = (unsigned short)mm; l.us[e] = (unsigned short)ll;
    }
    ((uint2*)hi)[i] = h.u2; ((uint2*)mi)[i] = m.u2; ((uint2*)lo)[i] = l.u2;
}

// ============ K1/K5: mem_update scan over T + bf16 spike transpose =========
__global__ __launch_bounds__(256) void scan_transpose(const float* __restrict__ src,
                                                      unsigned short* __restrict__ dstT) {
    __shared__ unsigned short tile[64][72];
    const int tid = threadIdx.x;
    const int l0 = blockIdx.x * 64, c0 = blockIdx.y * 64, b = blockIdx.z;
    const int row = tid >> 2, seg = tid & 3;
    float mem[16], sp[16];
#pragma unroll
    for (int e = 0; e < 16; e++) { mem[e] = 0.f; sp[e] = 0.f; }
    for (int t = 0; t < T_; t++) {
        const size_t base = ((size_t)((t*B_ + b)*C_ + c0 + row))*L_ + l0 + seg*16;
#pragma unroll
        for (int qq = 0; qq < 4; qq++) {
            float4 v = *(const float4*)(src + base + qq*4);
            float vv[4] = {v.x, v.y, v.z, v.w};
            unsigned bs[4];
#pragma unroll
            for (int s = 0; s < 4; s++) {
                int e = qq*4 + s;
                mem[e] = mem[e]*0.25f*(1.f - sp[e]) + vv[s];
                bool sb = mem[e] > 0.5f;
                sp[e] = sb ? 1.f : 0.f;
                bs[s] = sb ? 0x3F80u : 0u;
            }
            *(unsigned*)&tile[row][seg*16 + qq*4]     = bs[0] | (bs[1] << 16);
            *(unsigned*)&tile[row][seg*16 + qq*4 + 2] = bs[2] | (bs[3] << 16);
        }
        __syncthreads();
        {
            const int lr = tid >> 2, cs = tid & 3;
#pragma unroll
            for (int sub = 0; sub < 2; sub++) {
                unsigned wv[4];
#pragma unroll
                for (int p = 0; p < 4; p++) {
                    unsigned e0 = tile[cs*16 + sub*8 + p*2][lr];
                    unsigned e1 = tile[cs*16 + sub*8 + p*2 + 1][lr];
                    wv[p] = e0 | (e1 << 16);
                }
                uint4 o; o.x = wv[0]; o.y = wv[1]; o.z = wv[2]; o.w = wv[3];
                *(uint4*)(dstT + ((size_t)(t*B_ + b)*L_ + l0 + lr)*C_ + c0 + cs*16 + sub*8) = o;
            }
        }
        __syncthreads();
    }
}

// ============ K2: y = BN1(W @ xs) via MFMA, 96m x 64l tile, aliased LDS ====
__global__ __launch_bounds__(256) void gemm1_mfma(
    const unsigned short* __restrict__ whi, const unsigned short* __restrict__ wmi,
    const unsigned short* __restrict__ wlo, const unsigned short* __restrict__ xsT,
    const float* __restrict__ g, const float* __restrict__ be,
    const float* __restrict__ mn, const float* __restrict__ vr,
    unsigned short* __restrict__ y1hi, unsigned short* __restrict__ y1mi,
    unsigned short* __restrict__ y1lo,
    unsigned short* __restrict__ y2hi, unsigned short* __restrict__ y2mi,
    unsigned short* __restrict__ y2lo) {
    __shared__ unsigned short smem[14080];
    const int tid = threadIdx.x;
    const int flat = blockIdx.x;
    const int tb = flat & 7;
    const int ii = flat >> 3;
    const int mt = ii >> 4, lt = ii & 15;
    const int l0 = lt * 64;
    const int w = tid >> 6, lane = tid & 63;
    const int q = lane >> 4, n15 = lane & 15;
    const int mw = (w & 1) * 48, lw = (w >> 1) * 32;

    floatx4 acc[3][2];
#pragma unroll
    for (int i = 0; i < 3; i++)
#pragma unroll
        for (int j = 0; j < 2; j++) acc[i][j] = (floatx4){0.f,0.f,0.f,0.f};

    for (int ck = 0; ck < C_; ck += 32) {
#pragma unroll
        for (int p = 0; p < 3; p++) {
            const unsigned short* wp = p == 0 ? whi : p == 1 ? wmi : wlo;
            unsigned short* ap = smem + p*3840;
            for (int s = tid; s < 384; s += 256) {
                int r = s >> 2, c = s & 3;
                *(uint4*)&ap[r*40 + c*8] = *(const uint4*)(wp + (size_t)(mt*96 + r)*C_ + ck + c*8);
            }
        }
        {
            int r = tid >> 2, c = tid & 3;
            *(uint4*)&smem[11520 + r*40 + c*8] =
                *(const uint4*)(xsT + ((size_t)tb*L_ + l0 + r)*C_ + ck + c*8);
        }
        __syncthreads();
        short8 bb[2];
#pragma unroll
        for (int in = 0; in < 2; in++)
            bb[in] = *(short8*)&smem[11520 + (lw + in*16 + n15)*40 + q*8];
#pragma unroll
        for (int im = 0; im < 3; im++) {
            short8 ah = *(short8*)&smem[       (mw + im*16 + n15)*40 + q*8];
            short8 am = *(short8*)&smem[3840 + (mw + im*16 + n15)*40 + q*8];
            short8 al = *(short8*)&smem[7680 + (mw + im*16 + n15)*40 + q*8];
#pragma unroll
            for (int in = 0; in < 2; in++) {
                acc[im][in] = __builtin_amdgcn_mfma_f32_16x16x32_bf16(ah, bb[in], acc[im][in], 0,0,0);
                acc[im][in] = __builtin_amdgcn_mfma_f32_16x16x32_bf16(am, bb[in], acc[im][in], 0,0,0);
                acc[im][in] = __builtin_amdgcn_mfma_f32_16x16x32_bf16(al, bb[in], acc[im][in], 0,0,0);
            }
        }
        __syncthreads();
    }

#pragma unroll
    for (int im = 0; im < 3; im++)
#pragma unroll
        for (int r = 0; r < 4; r++) {
            int o = mt*96 + mw + im*16 + q*4 + r;
            float inv = g[o] / sqrtf(vr[o] + 1e-5f);
            float sh = be[o] - mn[o]*inv;
#pragma unroll
            for (int in = 0; in < 2; in++)
                acc[im][in][r] = acc[im][in][r]*inv + sh;
        }
    const bool isY1 = ((w & 1) == 0);
#pragma unroll
    for (int p = 0; p < 3; p++) {
        if (isY1) {
#pragma unroll
            for (int im = 0; im < 3; im++)
#pragma unroll
                for (int in = 0; in < 2; in++) {
                    union { unsigned short us[4]; uint2 u2; } pk;
#pragma unroll
                    for (int r = 0; r < 4; r++) {
                        unsigned hh = bf16_rne(acc[im][in][r]);
                        pk.us[r] = (unsigned short)hh;
                        acc[im][in][r] -= bf16_to_f(hh);
                    }
                    *(uint2*)&smem[(lw + in*16 + n15)*56 + im*16 + q*4] = pk.u2;
                }
        } else {
#pragma unroll
            for (int im = 0; im < 3; im++)
#pragma unroll
                for (int in = 0; in < 2; in++)
#pragma unroll
                    for (int r = 0; r < 4; r++) {
                        unsigned hh = bf16_rne(acc[im][in][r]);
                        smem[3584 + (im*16 + q*4 + r)*72 + lw + in*16 + n15] = (unsigned short)hh;
                        acc[im][in][r] -= bf16_to_f(hh);
                    }
        }
        __syncthreads();
        unsigned short* y1p = p == 0 ? y1hi : p == 1 ? y1mi : y1lo;
        unsigned short* y2p = p == 0 ? y2hi : p == 1 ? y2mi : y2lo;
        for (int s = tid; s < 384; s += 256) {
            int r1 = s / 6, c8 = s % 6;
            *(uint4*)(y1p + (((size_t)tb*H_ + mt)*L_ + l0 + r1)*48 + c8*8) =
                *(uint4*)&smem[r1*56 + c8*8];
        }
        for (int s = tid; s < 384; s += 256) {
            int cr = s >> 3, lq = s & 7;
            *(uint4*)(y2p + ((size_t)tb*C_ + mt*48 + cr)*L_ + l0 + lq*8) =
                *(uint4*)&smem[3584 + cr*72 + lq*8];
        }
        __syncthreads();
    }
}

// ============ K3: attn = y1^T @ xr (32x32x16 MFMA, K=48 exact) =============
// 64l x 64m tile, grid 4096 XCD-swizzled (2 bh slices per XCD)
__global__ __launch_bounds__(256) void attn_spike_mfma(
    const unsigned short* __restrict__ y1hi, const unsigned short* __restrict__ y1mi,
    const unsigned short* __restrict__ y1lo, const unsigned short* __restrict__ xsT,
    unsigned* __restrict__ bits) {
    __shared__ unsigned short A_hi[64][56], A_mi[64][56], A_lo[64][56], B_s[64][56];
    __shared__ unsigned bits_s[64][2];
    const int tid = threadIdx.x;
    const int flat = blockIdx.x;
    const int xcd = flat & 7;
    const int ii = flat >> 3;
    const int bh = xcd*2 + (ii >> 8);
    const int rr = ii & 255;
    const int b = bh >> 3, h = bh & 7;
    const int lbase = (rr >> 4)*64, mbase = (rr & 15)*64;
    const int w = tid >> 6, lane = tid & 63;
    const int l31 = lane & 31, half = lane >> 5;
    const int i = w & 1, j = w >> 1;

    float mem[16];
#pragma unroll
    for (int r = 0; r < 16; r++) mem[r] = 0.f;

    for (int t = 0; t < T_; t++) {
        const int tb = t*B_ + b;
        const size_t yb = (((size_t)tb*H_ + h)*L_ + lbase)*48;
        const size_t xb = ((size_t)tb*L_ + mbase)*C_ + h*48;
        for (int s = tid; s < 384; s += 256) {
            int r = s / 6, c = s % 6;
            size_t ro = yb + (size_t)r*48 + c*8;
            *(uint4*)&A_hi[r][c*8] = *(const uint4*)(y1hi + ro);
            *(uint4*)&A_mi[r][c*8] = *(const uint4*)(y1mi + ro);
            *(uint4*)&A_lo[r][c*8] = *(const uint4*)(y1lo + ro);
            *(uint4*)&B_s[r][c*8]  = *(const uint4*)(xsT + xb + (size_t)r*C_ + c*8);
        }
        if (tid < 128) bits_s[tid >> 1][tid & 1] = 0u;
        __syncthreads();

        floatx16 acc = {0.f,0.f,0.f,0.f,0.f,0.f,0.f,0.f,0.f,0.f,0.f,0.f,0.f,0.f,0.f,0.f};
#pragma unroll
        for (int ks = 0; ks < 3; ks++) {
            const int kcol = ks*16 + half*8;
            short8 bb = *(short8*)&B_s[j*32 + l31][kcol];
            short8 ah = *(short8*)&A_hi[i*32 + l31][kcol];
            short8 am = *(short8*)&A_mi[i*32 + l31][kcol];
            short8 al = *(short8*)&A_lo[i*32 + l31][kcol];
            acc = __builtin_amdgcn_mfma_f32_32x32x16_bf16(ah, bb, acc, 0,0,0);
            acc = __builtin_amdgcn_mfma_f32_32x32x16_bf16(am, bb, acc, 0,0,0);
            acc = __builtin_amdgcn_mfma_f32_32x32x16_bf16(al, bb, acc, 0,0,0);
        }

        unsigned word = 0;
#pragma unroll
        for (int r = 0; r < 16; r++) {
            float m = (mem[r] > 0.5f ? 0.f : mem[r]*0.25f) + acc[r];
            mem[r] = m;
            int lloc = (r & 3) + 8*(r >> 2) + 4*half;
            word |= (m > 0.5f) ? (1u << lloc) : 0u;
        }
        atomicOr(&bits_s[j*32 + l31][i], word);
        __syncthreads();
        if (tid < 128) {
            int m = tid >> 1, wd = tid & 1;
            bits[((size_t)(tb*H_ + h)*L_ + mbase + m)*32 + (lbase >> 5) + wd] = bits_s[m][wd];
        }
        __syncthreads();
    }
}

// ============ K4: outpre = y2 @ spikes (16x16x32, B unpacked from bits) ====
__global__ __launch_bounds__(256) void attn_out_mfma(
    const unsigned short* __restrict__ y2hi, const unsigned short* __restrict__ y2mi,
    const unsigned short* __restrict__ y2lo,
    const unsigned* __restrict__ bits, float* __restrict__ outpre) {
    __shared__ unsigned short A_hi[48][72], A_mi[48][72], A_lo[48][72];
    const int tid = threadIdx.x;
    const int flat = blockIdx.x;
    const int xcd = flat & 7;
    const int ii = flat >> 3;
    const int tbh = xcd*8 + (ii >> 4);
    const int mtile = ii & 15;
    const int t = tbh >> 4, b = (tbh >> 3) & 1, h = tbh & 7;
    const int tb = t*B_ + b;
    const int w = tid >> 6, lane = tid & 63;
    const int q = lane >> 4, n15 = lane & 15;
    const int mb = mtile*64 + w*16;

    floatx4 acc[3];
#pragma unroll
    for (int i = 0; i < 3; i++) acc[i] = (floatx4){0.f,0.f,0.f,0.f};

    const unsigned* brow = bits + ((size_t)(tb*H_ + h)*L_ + mb + n15)*32;
    const size_t y2b = ((size_t)tb*C_ + h*48)*L_;

    for (int lt = 0; lt < L_; lt += 64) {
        for (int s = tid; s < 384; s += 256) {
            int r = s >> 3, c = s & 7;
            size_t ro = y2b + (size_t)r*L_ + lt + c*8;
            *(uint4*)&A_hi[r][c*8] = *(const uint4*)(y2hi + ro);
            *(uint4*)&A_mi[r][c*8] = *(const uint4*)(y2mi + ro);
            *(uint4*)&A_lo[r][c*8] = *(const uint4*)(y2lo + ro);
        }
        uint2 bw = *(const uint2*)(brow + (lt >> 5));
        __syncthreads();
#pragma unroll
        for (int kc = 0; kc < 2; kc++) {
            unsigned word = kc ? bw.y : bw.x;
            unsigned byt = (word >> (q*8)) & 0xFFu;
            union { unsigned u[4]; short8 v; } bu;
#pragma unroll
            for (int p = 0; p < 4; p++)
                bu.u[p] = (((byt >> (2*p)) & 1u) ? 0x3F80u : 0u)
                        | (((byt >> (2*p+1)) & 1u) ? 0x3F800000u : 0u);
            short8 bfrag = bu.v;
#pragma unroll
            for (int i = 0; i < 3; i++) {
                int ra = i*16 + n15;
                short8 ah = *(short8*)&A_hi[ra][kc*32 + q*8];
                short8 am = *(short8*)&A_mi[ra][kc*32 + q*8];
                short8 al = *(short8*)&A_lo[ra][kc*32 + q*8];
                acc[i] = __builtin_amdgcn_mfma_f32_16x16x32_bf16(ah, bfrag, acc[i], 0,0,0);
                acc[i] = __builtin_amdgcn_mfma_f32_16x16x32_bf16(am, bfrag, acc[i], 0,0,0);
                acc[i] = __builtin_amdgcn_mfma_f32_16x16x32_bf16(al, bfrag, acc[i], 0,0,0);
            }
        }
        __syncthreads();
    }
#pragma unroll
    for (int i = 0; i < 3; i++)
#pragma unroll
        for (int r = 0; r < 4; r++) {
            int d = i*16 + q*4 + r;
            outpre[((size_t)tb*C_ + h*48 + d)*L_ + mb + n15] = acc[i][r];
        }
}

// ============ K6: out = BN2(proj @ outs) + x (MFMA, 96x64 tile) ============
__global__ __launch_bounds__(256) void gemm2_mfma(
    const unsigned short* __restrict__ whi, const unsigned short* __restrict__ wmi,
    const unsigned short* __restrict__ wlo, const unsigned short* __restrict__ xT,
    const float* __restrict__ g, const float* __restrict__ be,
    const float* __restrict__ mn, const float* __restrict__ vr,
    const float* __restrict__ res, float* __restrict__ out) {
    __shared__ unsigned short A_hi[96][40], A_mi[96][40], A_lo[96][40];
    __shared__ unsigned short B_s[64][40];
    const int tid = threadIdx.x;
    const int tb = blockIdx.y;
    const int mt = blockIdx.x >> 4, lt = blockIdx.x & 15;
    const int l0 = lt * 64;
    const int w = tid >> 6, lane = tid & 63;
    const int q = lane >> 4, n15 = lane & 15;
    const int mw = (w & 1) * 48, lw = (w >> 1) * 32;

    floatx4 acc[3][2];
#pragma unroll
    for (int i = 0; i < 3; i++)
#pragma unroll
        for (int j = 0; j < 2; j++) acc[i][j] = (floatx4){0.f,0.f,0.f,0.f};

    for (int ck = 0; ck < C_; ck += 32) {
#pragma unroll
        for (int p = 0; p < 3; p++) {
            const unsigned short* wp = p == 0 ? whi : p == 1 ? wmi : wlo;
            unsigned short (*ap)[40] = p == 0 ? A_hi : p == 1 ? A_mi : A_lo;
            for (int s = tid; s < 384; s += 256) {
                int r = s >> 2, c = s & 3;
                *(uint4*)&ap[r][c*8] = *(const uint4*)(wp + (size_t)(mt*96 + r)*C_ + ck + c*8);
            }
        }
        {
            int r = tid >> 2, c4 = tid & 3;
            *(uint4*)&B_s[r][c4*8] = *(const uint4*)(xT + ((size_t)tb*L_ + l0 + r)*C_ + ck + c4*8);
        }
        __syncthreads();
        short8 bb[2];
#pragma unroll
        for (int in = 0; in < 2; in++)
            bb[in] = *(short8*)&B_s[lw + in*16 + n15][q*8];
#pragma unroll
        for (int im = 0; im < 3; im++) {
            short8 ah = *(short8*)&A_hi[mw + im*16 + n15][q*8];
            short8 am = *(short8*)&A_mi[mw + im*16 + n15][q*8];
            short8 al = *(short8*)&A_lo[mw + im*16 + n15][q*8];
#pragma unroll
            for (int in = 0; in < 2; in++) {
                acc[im][in] = __builtin_amdgcn_mfma_f32_16x16x32_bf16(ah, bb[in], acc[im][in], 0,0,0);
                acc[im][in] = __builtin_amdgcn_mfma_f32_16x16x32_bf16(am, bb[in], acc[im][in], 0,0,0);
                acc[im][in] = __builtin_amdgcn_mfma_f32_16x16x32_bf16(al, bb[in], acc[im][in], 0,0,0);
            }
        }
        __syncthreads();
    }
#pragma unroll
    for (int im = 0; im < 3; im++)
#pragma unroll
        for (int r = 0; r < 4; r++) {
            int o = mt*96 + mw + im*16 + q*4 + r;
            float inv = g[o] / sqrtf(vr[o] + 1e-5f);
            float sh = be[o] - mn[o]*inv;
#pragma unroll
            for (int in = 0; in < 2; in++) {
                int l = l0 + lw + in*16 + n15;
                size_t idx = ((size_t)tb*C_ + o)*L_ + l;
                out[idx] = acc[im][in][r]*inv + sh + res[idx];
            }
        }
}

extern "C" void kernel_launch(void* const* d_in, const int* in_sizes, int n_in,
                              void* d_out, int out_size, void* d_ws, size_t ws_size,
                              hipStream_t stream) {
    const float* x   = (const float*)d_in[0];
    const float* W_w = (const float*)d_in[1];
    const float* g1  = (const float*)d_in[2];
    const float* b1  = (const float*)d_in[3];
    const float* m1  = (const float*)d_in[4];
    const float* v1  = (const float*)d_in[5];
    const float* pw  = (const float*)d_in[6];
    const float* g2  = (const float*)d_in[7];
    const float* b2  = (const float*)d_in[8];
    const float* m2  = (const float*)d_in[9];
    const float* v2  = (const float*)d_in[10];

    float* ws = (float*)d_ws;
    unsigned short* xsT  = (unsigned short*)ws;               // 1,572,864 f
    unsigned short* y1hi = (unsigned short*)(ws + 1572864);   // 1,572,864 f each
    unsigned short* y1mi = (unsigned short*)(ws + 3145728);
    unsigned short* y1lo = (unsigned short*)(ws + 4718592);
    unsigned short* y2hi = (unsigned short*)(ws + 6291456);
    unsigned short* y2mi = (unsigned short*)(ws + 7864320);
    unsigned short* y2lo = (unsigned short*)(ws + 9437184);
    unsigned*       bits = (unsigned*)(ws + 11010048);        // ends 13,107,200 f
    unsigned short* wspl[3]  = {(unsigned short*)(ws + 13107200),
                                (unsigned short*)(ws + 13254656),
                                (unsigned short*)(ws + 13402112)};
    unsigned short* pwspl[3] = {(unsigned short*)(ws + 13549568),
                                (unsigned short*)(ws + 13623296),
                                (unsigned short*)(ws + 13697024)};  // ends 13,770,752 f = 55.1 MB
    float*          outpre = (float*)(ws + 1572864);          // alias y1hi+y1mi (dead after K3)
    unsigned short* outsT  = (unsigned short*)(ws + 4718592); // alias y1lo (dead after K3)
    float* out = (float*)d_out;

    // 0) split both weight tensors into bf16 planes (one launch)
    split_w2<<<dim3(432), 256, 0, stream>>>(W_w, C2_*C_/4, wspl[0], wspl[1], wspl[2],
                                            pw,  C_*C_/4, pwspl[0], pwspl[1], pwspl[2]);
    // 1) xs spikes (exact fp32 scan) -> bf16, transposed [tb][l][c]
    scan_transpose<<<dim3(16, 6, B_), 256, 0, stream>>>(x, xsT);
    // 2) y = BN1(W @ xs): 96x64 tile, aliased LDS, 1024 blocks XCD-swizzled
    gemm1_mfma<<<dim3(1024), 256, 0, stream>>>(wspl[0], wspl[1], wspl[2], xsT,
                                               g1, b1, m1, v1,
                                               y1hi, y1mi, y1lo, y2hi, y2mi, y2lo);
    // 3) attn spikes: 64x64 tile, grid 4096 XCD-swizzled
    attn_spike_mfma<<<dim3(4096), 256, 0, stream>>>(y1hi, y1mi, y1lo, xsT, bits);
    // 4) outpre = y2 @ spikes: MFMA, XCD-swizzled 1D grid
    attn_out_mfma<<<dim3(1024), 256, 0, stream>>>(y2hi, y2mi, y2lo, bits, outpre);
    // 5) outs spikes -> bf16 transposed
    scan_transpose<<<dim3(16, 6, B_), 256, 0, stream>>>(outpre, outsT);
    // 6) out = BN2(proj @ outs) + x
    gemm2_mfma<<<dim3(64, 8), 256, 0, stream>>>(pwspl[0], pwspl[1], pwspl[2], outsT,
                                                g2, b2, m2, v2, x, out);
}